// Round 3
// baseline (846.080 us; speedup 1.0000x reference)
//
#include <hip/hip_runtime.h>

#define NN 100000   // nodes
#define NE 3200000  // edges
#define NF 512      // in features
#define NH 16       // hidden
#define NC 7        // classes

#define NB   1024           // dst buckets
#define SPAN 98             // nodes per bucket (1024*98 = 100352 >= NN)
#define NBLK 256            // blocks for the edge-partition passes
#define EPB  (NE / NBLK)    // 12500 edges per block (exact)

// ---------------------------------------------------------------------------
// GEMM1: h0[n, 0:16] = x[n, 0:512] @ W1[512,16].  One wave per row.
// W1 rows for each lane's k-slice live in registers (128 VGPRs).
// ---------------------------------------------------------------------------
__global__ __launch_bounds__(256) void gemm1_kernel(const float* __restrict__ x,
                                                    const float* __restrict__ W1,
                                                    float* __restrict__ h0) {
  const int lane = threadIdx.x & 63;
  const int wave = (blockIdx.x * blockDim.x + threadIdx.x) >> 6;
  const int nwaves = (gridDim.x * blockDim.x) >> 6;

  float w[8][NH];
#pragma unroll
  for (int i = 0; i < 4; ++i) {
#pragma unroll
    for (int j = 0; j < NH; ++j) {
      w[i][j]     = W1[(4 * lane + i) * NH + j];
      w[4 + i][j] = W1[(256 + 4 * lane + i) * NH + j];
    }
  }

  for (int row = wave; row < NN; row += nwaves) {
    const float4* xr = (const float4*)(x + (size_t)row * NF);
    float4 a0 = xr[lane];
    float4 a1 = xr[64 + lane];
    float a[8] = {a0.x, a0.y, a0.z, a0.w, a1.x, a1.y, a1.z, a1.w};

    float acc[NH];
#pragma unroll
    for (int j = 0; j < NH; ++j) acc[j] = 0.f;
#pragma unroll
    for (int i = 0; i < 8; ++i) {
#pragma unroll
      for (int j = 0; j < NH; ++j) acc[j] += a[i] * w[i][j];
    }

    float outv = 0.f;
#pragma unroll
    for (int j = 0; j < NH; ++j) {
      float v = acc[j];
      v += __shfl_xor(v, 1);
      v += __shfl_xor(v, 2);
      v += __shfl_xor(v, 4);
      v += __shfl_xor(v, 8);
      v += __shfl_xor(v, 16);
      v += __shfl_xor(v, 32);
      if (lane == j) outv = v;
    }
    if (lane < NH) h0[(size_t)row * NH + lane] = outv;
  }
}

// ===========================================================================
// Bucket partition: edges -> dst-bucket-ordered packed records
//   record = src (bits 0..16) | dstLocal (bits 17..23), 4B each
// ===========================================================================
__global__ __launch_bounds__(512) void countK(const int* __restrict__ ei,
                                              int* __restrict__ bucketCount,
                                              int* __restrict__ blockBase) {
  __shared__ int cnt[NB];
  const int b = blockIdx.x, tid = threadIdx.x;
  for (int i = tid; i < NB; i += 512) cnt[i] = 0;
  __syncthreads();
  const int base = b * EPB;
  for (int e = tid; e < EPB; e += 512) {
    int d = ei[NE + base + e];
    atomicAdd(&cnt[d / SPAN], 1);
  }
  __syncthreads();
  for (int i = tid; i < NB; i += 512) {
    int c = cnt[i];
    blockBase[b * NB + i] = c ? atomicAdd(&bucketCount[i], c) : 0;
  }
}

__global__ __launch_bounds__(1024) void scanK(const int* __restrict__ bucketCount,
                                              int* __restrict__ bucketOffs) {
  __shared__ int sm[NB];
  const int t = threadIdx.x;     // blockDim == NB == 1024
  int v = bucketCount[t];
  sm[t] = v;
  __syncthreads();
  for (int off = 1; off < NB; off <<= 1) {
    int u = (t >= off) ? sm[t - off] : 0;
    __syncthreads();
    sm[t] += u;
    __syncthreads();
  }
  bucketOffs[t] = sm[t] - v;     // exclusive
  if (t == NB - 1) bucketOffs[NB] = NE;
}

__global__ __launch_bounds__(512) void scatK(const int* __restrict__ ei,
                                             const int* __restrict__ bucketOffs,
                                             const int* __restrict__ blockBase,
                                             unsigned* __restrict__ pairs) {
  __shared__ int cur[NB];
  const int b = blockIdx.x, tid = threadIdx.x;
  for (int i = tid; i < NB; i += 512) cur[i] = 0;
  __syncthreads();
  const int base = b * EPB;
  for (int e = tid; e < EPB; e += 512) {
    int s = ei[base + e];
    int d = ei[NE + base + e];
    int j = d / SPAN;
    int dl = d - j * SPAN;
    int r = atomicAdd(&cur[j], 1);
    pairs[bucketOffs[j] + blockBase[b * NB + j] + r] = (unsigned)s | ((unsigned)dl << 17);
  }
}

// ===========================================================================
// Layer-1 aggregate: one block per bucket, LDS accumulator [SPAN][16].
// 16 lanes per edge (col = tid&15) -> 64B coalesced gather of h0 row.
// 4x unrolled: 4 independent pk loads + 4 independent gathers in flight.
// ===========================================================================
__global__ __launch_bounds__(512) void agg16K(const int* __restrict__ bucketOffs,
                                              const unsigned* __restrict__ pairs,
                                              const float* __restrict__ h0,
                                              float* __restrict__ agg) {
  __shared__ float acc[SPAN * NH];   // 6272 B
  const int j = blockIdx.x, tid = threadIdx.x;
  for (int i = tid; i < SPAN * NH; i += 512) acc[i] = 0.f;
  __syncthreads();
  const int beg = bucketOffs[j], end = bucketOffs[j + 1];
  const int col = tid & 15, slot = tid >> 4;   // 32 edge slots
  int e = beg + slot;
  for (; e + 96 < end; e += 128) {             // 4x unroll, stride 32 per slot
    unsigned pk0 = pairs[e];
    unsigned pk1 = pairs[e + 32];
    unsigned pk2 = pairs[e + 64];
    unsigned pk3 = pairs[e + 96];
    float v0 = h0[(size_t)(pk0 & 0x1FFFF) * NH + col];
    float v1 = h0[(size_t)(pk1 & 0x1FFFF) * NH + col];
    float v2 = h0[(size_t)(pk2 & 0x1FFFF) * NH + col];
    float v3 = h0[(size_t)(pk3 & 0x1FFFF) * NH + col];
    atomicAdd(&acc[(pk0 >> 17) * NH + col], v0);
    atomicAdd(&acc[(pk1 >> 17) * NH + col], v1);
    atomicAdd(&acc[(pk2 >> 17) * NH + col], v2);
    atomicAdd(&acc[(pk3 >> 17) * NH + col], v3);
  }
  for (; e < end; e += 32) {
    unsigned pk = pairs[e];
    atomicAdd(&acc[(pk >> 17) * NH + col], h0[(size_t)(pk & 0x1FFFF) * NH + col]);
  }
  __syncthreads();
  const int lo = j * SPAN;
  for (int i = tid; i < SPAN * NH; i += 512) {
    int node = lo + (i >> 4);
    if (node < NN) agg[(size_t)node * NH + (i & 15)] = acc[i];
  }
}

// ---------------------------------------------------------------------------
// Per-node transform: p[n, 0:7] = relu(agg1[n] + b1) @ W2, p stride 8.
// ---------------------------------------------------------------------------
__global__ __launch_bounds__(256) void transform_kernel(const float* __restrict__ agg1,
                                                        const float* __restrict__ b1,
                                                        const float* __restrict__ W2,
                                                        float* __restrict__ p) {
  int n = blockIdx.x * blockDim.x + threadIdx.x;
  if (n >= NN) return;
  const float4* r = (const float4*)(agg1 + (size_t)n * NH);
  float4 v0 = r[0], v1 = r[1], v2 = r[2], v3 = r[3];
  float h[NH] = {v0.x, v0.y, v0.z, v0.w, v1.x, v1.y, v1.z, v1.w,
                 v2.x, v2.y, v2.z, v2.w, v3.x, v3.y, v3.z, v3.w};
#pragma unroll
  for (int k = 0; k < NH; ++k) h[k] = fmaxf(h[k] + b1[k], 0.f);

#pragma unroll
  for (int j = 0; j < NC; ++j) {
    float acc = 0.f;
#pragma unroll
    for (int k = 0; k < NH; ++k) acc += h[k] * W2[k * NC + j];
    p[(size_t)n * 8 + j] = acc;
  }
  p[(size_t)n * 8 + 7] = 0.f;   // pad col must be clean: agg8K accumulates it
}

// ===========================================================================
// Layer-2 aggregate: LDS accumulator [SPAN][8]; 8 lanes per edge, 4x unroll.
// ===========================================================================
__global__ __launch_bounds__(512) void agg8K(const int* __restrict__ bucketOffs,
                                             const unsigned* __restrict__ pairs,
                                             const float* __restrict__ p,
                                             float* __restrict__ agg) {
  __shared__ float acc[SPAN * 8];    // 3136 B
  const int j = blockIdx.x, tid = threadIdx.x;
  for (int i = tid; i < SPAN * 8; i += 512) acc[i] = 0.f;
  __syncthreads();
  const int beg = bucketOffs[j], end = bucketOffs[j + 1];
  const int col = tid & 7, slot = tid >> 3;    // 64 edge slots
  int e = beg + slot;
  for (; e + 192 < end; e += 256) {            // 4x unroll, stride 64 per slot
    unsigned pk0 = pairs[e];
    unsigned pk1 = pairs[e + 64];
    unsigned pk2 = pairs[e + 128];
    unsigned pk3 = pairs[e + 192];
    float v0 = p[(size_t)(pk0 & 0x1FFFF) * 8 + col];
    float v1 = p[(size_t)(pk1 & 0x1FFFF) * 8 + col];
    float v2 = p[(size_t)(pk2 & 0x1FFFF) * 8 + col];
    float v3 = p[(size_t)(pk3 & 0x1FFFF) * 8 + col];
    atomicAdd(&acc[(pk0 >> 17) * 8 + col], v0);
    atomicAdd(&acc[(pk1 >> 17) * 8 + col], v1);
    atomicAdd(&acc[(pk2 >> 17) * 8 + col], v2);
    atomicAdd(&acc[(pk3 >> 17) * 8 + col], v3);
  }
  for (; e < end; e += 64) {
    unsigned pk = pairs[e];
    atomicAdd(&acc[(pk >> 17) * 8 + col], p[(size_t)(pk & 0x1FFFF) * 8 + col]);
  }
  __syncthreads();
  const int lo = j * SPAN;
  for (int i = tid; i < SPAN * 8; i += 512) {
    int node = lo + (i >> 3);
    if (node < NN) agg[(size_t)node * 8 + (i & 7)] = acc[i];
  }
}

// ---------------------------------------------------------------------------
// log_softmax over 7 classes; agg2 stride 8 in, out stride 7.
// ---------------------------------------------------------------------------
__global__ __launch_bounds__(256) void lsm_kernel(const float* __restrict__ agg2,
                                                  const float* __restrict__ b2,
                                                  float* __restrict__ out) {
  int n = blockIdx.x * blockDim.x + threadIdx.x;
  if (n >= NN) return;
  float z[NC];
  float m = -1e30f;
#pragma unroll
  for (int j = 0; j < NC; ++j) {
    z[j] = agg2[(size_t)n * 8 + j] + b2[j];
    m = fmaxf(m, z[j]);
  }
  float s = 0.f;
#pragma unroll
  for (int j = 0; j < NC; ++j) s += __expf(z[j] - m);
  float l = __logf(s);
#pragma unroll
  for (int j = 0; j < NC; ++j) out[(size_t)n * NC + j] = z[j] - m - l;
}

// ===========================================================================
// Legacy atomic-scatter path (fallback when workspace is too small).
// ===========================================================================
__global__ __launch_bounds__(256) void scatter16_kernel(const int* __restrict__ ei,
                                                        const float* __restrict__ h0,
                                                        float* __restrict__ agg) {
  long long gid = (long long)blockIdx.x * blockDim.x + threadIdx.x;
  int e = (int)(gid >> 4);
  if (e >= NE) return;
  int j = (int)(gid & 15);
  int s = ei[e];
  int d = ei[NE + e];
  atomicAdd(&agg[(size_t)d * NH + j], h0[(size_t)s * NH + j]);
}

__global__ __launch_bounds__(256) void scatter7_kernel(const int* __restrict__ ei,
                                                       const float* __restrict__ p,
                                                       float* __restrict__ agg) {
  long long gid = (long long)blockIdx.x * blockDim.x + threadIdx.x;
  int e = (int)(gid >> 3);
  if (e >= NE) return;
  int j = (int)(gid & 7);
  if (j >= NC) return;
  int s = ei[e];
  int d = ei[NE + e];
  atomicAdd(&agg[(size_t)d * 8 + j], p[(size_t)s * 8 + j]);
}

extern "C" void kernel_launch(void* const* d_in, const int* in_sizes, int n_in,
                              void* d_out, int out_size, void* d_ws, size_t ws_size,
                              hipStream_t stream) {
  const float* x  = (const float*)d_in[0];
  const int*   ei = (const int*)d_in[1];   // [2, NE] int32: src row then dst row
  const float* W1 = (const float*)d_in[2];
  const float* b1 = (const float*)d_in[3];
  const float* W2 = (const float*)d_in[4];
  const float* b2 = (const float*)d_in[5];
  float* out = (float*)d_out;

  // ws layout (25.6 MB):
  //   h0p   : NN*16 f32 (6.4 MB)  -- h0, later reused as p (stride 8)
  //   aggp  : NN*16 f32 (6.4 MB)  -- agg1 / agg2; first 1 MB aliases blockBase
  //   pairs : NE  u32 (12.8 MB)   -- bucket-ordered packed (src | dl<<17)
  //   bucketCount[NB], bucketOffs[NB+1]
  float*    h0p  = (float*)d_ws;
  float*    aggp = h0p + (size_t)NN * NH;
  unsigned* pairs = (unsigned*)(aggp + (size_t)NN * NH);
  int* bucketCount = (int*)(pairs + NE);
  int* bucketOffs  = bucketCount + NB;
  int* blockBase   = (int*)aggp;          // NBLK*NB ints = 1 MB, dead before agg16K
  size_t need = (size_t)((char*)(bucketOffs + NB + 1) - (char*)d_ws);

  if (ws_size >= need) {
    hipMemsetAsync(bucketCount, 0, NB * sizeof(int), stream);
    countK<<<NBLK, 512, 0, stream>>>(ei, bucketCount, blockBase);
    scanK<<<1, NB, 0, stream>>>(bucketCount, bucketOffs);
    scatK<<<NBLK, 512, 0, stream>>>(ei, bucketOffs, blockBase, pairs);

    gemm1_kernel<<<2048, 256, 0, stream>>>(x, W1, h0p);
    agg16K<<<NB, 512, 0, stream>>>(bucketOffs, pairs, h0p, aggp);
    transform_kernel<<<(NN + 255) / 256, 256, 0, stream>>>(aggp, b1, W2, h0p);
    agg8K<<<NB, 512, 0, stream>>>(bucketOffs, pairs, h0p, aggp);
    lsm_kernel<<<(NN + 255) / 256, 256, 0, stream>>>(aggp, b2, out);
  } else {
    // ---- legacy path (12.8 MB ws): verified at 705 us ----
    float* bufA = (float*)d_ws;
    float* bufB = bufA + (size_t)NN * NH;

    hipMemsetAsync(bufB, 0, (size_t)NN * NH * sizeof(float), stream);
    gemm1_kernel<<<2048, 256, 0, stream>>>(x, W1, bufA);
    scatter16_kernel<<<(int)(((long long)NE * 16 + 255) / 256), 256, 0, stream>>>(ei, bufA, bufB);
    transform_kernel<<<(NN + 255) / 256, 256, 0, stream>>>(bufB, b1, W2, bufA);
    hipMemsetAsync(bufB, 0, (size_t)NN * 8 * sizeof(float), stream);
    scatter7_kernel<<<(int)(((long long)NE * 8 + 255) / 256), 256, 0, stream>>>(ei, bufA, bufB);
    lsm_kernel<<<(NN + 255) / 256, 256, 0, stream>>>(bufB, b2, out);
  }
}